// Round 1
// baseline (47.472 us; speedup 1.0000x reference)
//
#include <hip/hip_runtime.h>
#include <math.h>

#define NROWS 262144
#define DDIM 64
#define NPROT 512
#define NBLK 1024  // 256 rows per block
#define MAGIC 0x5A17C0DEu

typedef __attribute__((ext_vector_type(8))) short short8;
typedef __attribute__((ext_vector_type(4))) float f32x4;

__device__ __forceinline__ unsigned cvt_pk_bf16(float lo, float hi) {
    unsigned r;
    asm("v_cvt_pk_bf16_f32 %0, %1, %2" : "=v"(r) : "v"(lo), "v"(hi));
    return r;
}

// v = min(v, dpp-permuted v); CTRL compile-time (0xB1 xor1, 0x4E xor2,
// 0x141 row_half_mirror = xor4, 0x140 row_mirror = xor8) — within 16-lane rows
template <int CTRL>
__device__ __forceinline__ float dpp_min(float v) {
    int s = __builtin_amdgcn_update_dpp(__float_as_int(v), __float_as_int(v),
                                        CTRL, 0xF, 0xF, true);
    return fminf(v, __int_as_float(s));
}

// ---- single fused kernel: per-block proto conversion + main + flag-tail ----
__global__ __launch_bounds__(256, 2) void glvq_fused(
    const float* __restrict__ x,
    const float* __restrict__ protos,
    const int* __restrict__ y,
    float* __restrict__ partial,
    unsigned* __restrict__ flags,
    float* __restrict__ out)
{
    __shared__ uint4 s_pb[NPROT * 8];   // 64 KB: all bf16(-2p) protos, swizzled
    __shared__ float s_psq[NPROT];      // 2 KB, [jj][col][t]
    __shared__ float s_xsq[4][64];      // 1 KB
    __shared__ int   s_y[256];          // 1 KB
    __shared__ float s_red[4];

    const int tid = threadIdx.x;
    const int lane = tid & 63, w = tid >> 6;
    const int g = lane >> 4, col = lane & 15;
    const int row0 = blockIdx.x * 256;

    // x loads first (HBM latency-critical): row = row0 + w*64 + rt*16 + col
    float4 raw[16];
    {
        const float* xb = x + (size_t)(row0 + w * 64 + col) * DDIM;
#pragma unroll
        for (int rt = 0; rt < 4; ++rt)
#pragma unroll
            for (int kk = 0; kk < 2; ++kk) {
                raw[rt * 4 + kk * 2 + 0] =
                    *reinterpret_cast<const float4*>(xb + rt * 1024 + kk * 32 + g * 8);
                raw[rt * 4 + kk * 2 + 1] =
                    *reinterpret_cast<const float4*>(xb + rt * 1024 + kk * 32 + g * 8 + 4);
            }
    }

    // fused proto conversion (was glvq_prep + L2 staging): 2 protos per thread.
    // p = (jj + 8t)*16 + pc; slot = jj*64 + t*16 + pc; protos array is L2-resident
    // after first touch (128 KB), conversion hides under the in-flight x loads.
#pragma unroll
    for (int h = 0; h < 2; ++h) {
        const int p = tid + h * 256;
        const int jj = (p >> 4) & 7, pc = p & 15, t = p >> 7;
        const int slot = jj * 64 + t * 16 + pc;
        const float* pr = protos + p * DDIM;
        float sq = 0.f;
#pragma unroll
        for (int c = 0; c < 8; ++c) {
            float4 v0 = *reinterpret_cast<const float4*>(pr + c * 8);
            float4 v1 = *reinterpret_cast<const float4*>(pr + c * 8 + 4);
            sq += v0.x * v0.x + v0.y * v0.y + v0.z * v0.z + v0.w * v0.w +
                  v1.x * v1.x + v1.y * v1.y + v1.z * v1.z + v1.w * v1.w;
            union { unsigned u[4]; uint4 q; } pk;
            pk.u[0] = cvt_pk_bf16(-2.f * v0.x, -2.f * v0.y);
            pk.u[1] = cvt_pk_bf16(-2.f * v0.z, -2.f * v0.w);
            pk.u[2] = cvt_pk_bf16(-2.f * v1.x, -2.f * v1.y);
            pk.u[3] = cvt_pk_bf16(-2.f * v1.z, -2.f * v1.w);
            s_pb[(slot * 8 + c) ^ (slot & 7)] = pk.q;
        }
        // psq layout: [jj (8)][pc (16)][t (4)]
        s_psq[jj * 64 + pc * 4 + t] = sq;
    }
    s_y[tid] = y[row0 + tid];

    // convert x to A fragments + row norms
    short8 afrag[4][2];
#pragma unroll
    for (int rt = 0; rt < 4; ++rt) {
        float part = 0.f;
#pragma unroll
        for (int kk = 0; kk < 2; ++kk) {
            float4 a0 = raw[rt * 4 + kk * 2 + 0];
            float4 a1 = raw[rt * 4 + kk * 2 + 1];
            part += a0.x * a0.x + a0.y * a0.y + a0.z * a0.z + a0.w * a0.w +
                    a1.x * a1.x + a1.y * a1.y + a1.z * a1.z + a1.w * a1.w;
            union { unsigned u[4]; short8 s; } pk;
            pk.u[0] = cvt_pk_bf16(a0.x, a0.y);
            pk.u[1] = cvt_pk_bf16(a0.z, a0.w);
            pk.u[2] = cvt_pk_bf16(a1.x, a1.y);
            pk.u[3] = cvt_pk_bf16(a1.z, a1.w);
            afrag[rt][kk] = pk.s;
        }
        part += __shfl_xor(part, 16);
        part += __shfl_xor(part, 32);
        if (g == 0) s_xsq[w][rt * 16 + col] = part;
    }

    __syncthreads();  // protos/psq/y visible; only barrier before the end

    // corr <=> jcv[rt][r] == jj
    int jcv[4][4];
#pragma unroll
    for (int rt = 0; rt < 4; ++rt)
#pragma unroll
        for (int r = 0; r < 4; ++r) {
            int yv = s_y[w * 64 + rt * 16 + g * 4 + r];
            jcv[rt][r] = ((yv & 15) == col) ? (yv >> 4) : 15;
        }

    float m1[4][4], m2[4][4];
#pragma unroll
    for (int rt = 0; rt < 4; ++rt)
#pragma unroll
        for (int r = 0; r < 4; ++r) { m1[rt][r] = INFINITY; m2[rt][r] = INFINITY; }

    // per-lane constant LDS bases; t offsets fold into ds immediates
    const int sw = (col & 7) << 4;
    const char* s_pb_c = (const char*)s_pb;
    const char* pb0 = s_pb_c + col * 128 + ((g * 16) ^ sw);
    const char* pb1 = s_pb_c + col * 128 + ((g * 16 + 64) ^ sw);
    const char* pqc = (const char*)s_psq + col * 16;

#pragma unroll
    for (int jj = 0; jj < 8; ++jj) {
        // de-convoy: each wave walks the proto tiles in a rotated order
        const int jjr = (jj + 2 * w) & 7;
        const int bj = jjr * 8192;
        const f32x4 psqv = *reinterpret_cast<const f32x4*>(pqc + jjr * 256);
        float vmin[4][4];
#pragma unroll
        for (int rt = 0; rt < 4; ++rt)
#pragma unroll
            for (int r = 0; r < 4; ++r) vmin[rt][r] = INFINITY;
#pragma unroll
        for (int t = 0; t < 4; ++t) {
            short8 b0 = *reinterpret_cast<const short8*>(pb0 + bj + t * 2048);
            short8 b1 = *reinterpret_cast<const short8*>(pb1 + bj + t * 2048);
            const float sd = psqv[t];
#pragma unroll
            for (int rt = 0; rt < 4; ++rt) {
                f32x4 a = {sd, sd, sd, sd};  // seed acc with ||p||^2
                a = __builtin_amdgcn_mfma_f32_16x16x32_bf16(afrag[rt][0], b0, a, 0, 0, 0);
                a = __builtin_amdgcn_mfma_f32_16x16x32_bf16(afrag[rt][1], b1, a, 0, 0, 0);
#pragma unroll
                for (int r = 0; r < 4; ++r)
                    vmin[rt][r] = fminf(vmin[rt][r], a[r]);
            }
        }
#pragma unroll
        for (int rt = 0; rt < 4; ++rt)
#pragma unroll
            for (int r = 0; r < 4; ++r) {
                float v = vmin[rt][r];
                bool corr = (jcv[rt][r] == jjr);
                m1[rt][r] = corr ? v : m1[rt][r];                  // hits exactly once
                m2[rt][r] = corr ? m2[rt][r] : fminf(m2[rt][r], v);
            }
    }

    // epilogue: DPP min over 16 proto-columns, mu/sigmoid
    float lsum = 0.f;
#pragma unroll
    for (int rt = 0; rt < 4; ++rt)
#pragma unroll
        for (int r = 0; r < 4; ++r) {
            float a1 = m1[rt][r], a2 = m2[rt][r];
            a1 = dpp_min<0xB1>(a1);  a2 = dpp_min<0xB1>(a2);   // xor 1
            a1 = dpp_min<0x4E>(a1);  a2 = dpp_min<0x4E>(a2);   // xor 2
            a1 = dpp_min<0x141>(a1); a2 = dpp_min<0x141>(a2);  // xor 4
            a1 = dpp_min<0x140>(a1); a2 = dpp_min<0x140>(a2);  // xor 8
            float xsq = s_xsq[w][rt * 16 + g * 4 + r];
            float d1 = xsq + a1, d2 = xsq + a2;
            float mu = (d1 - d2) / (d1 + d2 + 1e-9f);
            float sig = 1.f / (1.f + __expf(-mu));
            lsum += (col == 0) ? sig : 0.f;
        }
#pragma unroll
    for (int mk = 1; mk <= 32; mk <<= 1) lsum += __shfl_xor(lsum, mk);
    if (lane == 0) s_red[w] = lsum;
    __syncthreads();

    // publish partial: agent-scope store-through + release flag (ws is poisoned,
    // so readiness is signalled by MAGIC, no pre-zeroed counter needed)
    if (tid == 0) {
        float bsum = (s_red[0] + s_red[1]) + (s_red[2] + s_red[3]);
        __hip_atomic_store(&partial[blockIdx.x], bsum,
                           __ATOMIC_RELAXED, __HIP_MEMORY_SCOPE_AGENT);
        __hip_atomic_store(&flags[blockIdx.x], MAGIC,
                           __ATOMIC_RELEASE, __HIP_MEMORY_SCOPE_AGENT);
    }

    // block 0 polls all flags, then does the final reduction (replaces finalize
    // kernel). Polling never blocks producers: 2 blocks/CU co-resident, the
    // other 511 slots keep draining blocks 1..1023.
    if (blockIdx.x == 0) {
        float acc = 0.f;
#pragma unroll
        for (int i = tid; i < NBLK; i += 256) {
            while (__hip_atomic_load(&flags[i], __ATOMIC_ACQUIRE,
                                     __HIP_MEMORY_SCOPE_AGENT) != MAGIC)
                __builtin_amdgcn_s_sleep(2);
            acc += __hip_atomic_load(&partial[i], __ATOMIC_RELAXED,
                                     __HIP_MEMORY_SCOPE_AGENT);
        }
        __syncthreads();  // s_red reads above are done; safe to reuse
#pragma unroll
        for (int mk = 1; mk <= 32; mk <<= 1) acc += __shfl_xor(acc, mk);
        if (lane == 0) s_red[w] = acc;
        __syncthreads();
        if (tid == 0)
            out[0] = ((s_red[0] + s_red[1]) + (s_red[2] + s_red[3])) *
                     (1.0f / (float)NROWS);
    }
}

extern "C" void kernel_launch(void* const* d_in, const int* in_sizes, int n_in,
                              void* d_out, int out_size, void* d_ws, size_t ws_size,
                              hipStream_t stream) {
    const float* x = (const float*)d_in[0];
    const float* protos = (const float*)d_in[1];
    const int* y = (const int*)d_in[2];
    float* out = (float*)d_out;

    // ws layout: [0..4K) partials | [4K..8K) ready flags
    float* partial = (float*)d_ws;
    unsigned* flags = (unsigned*)((char*)d_ws + 4096);

    glvq_fused<<<NBLK, 256, 0, stream>>>(x, protos, y, partial, flags, out);
}